// Round 1
// baseline (1819.190 us; speedup 1.0000x reference)
//
#include <hip/hip_runtime.h>
#include <cstdint>
#include <cstddef>

// ---------------------------------------------------------------------------
// GATv2 edge predictor, fp32 throughout.
// Pipeline:
//   0. memset cnt/loop_sum
//   1. degree_kernel: cnt[dst]++, loop_sum[dst] += edge_attr   (atomics, E*16 thr)
//   2. loop_attr_kernel: loop_sum /= max(cnt,1)   (self-loop attr, fill='mean')
//   3. scan_kernel: rowptr = exscan(cnt+1)  (single block)
//   4. csr_build: scatter edge ids by dst -> eperm/sperm/dperm  (CSR by dst)
//   per GAT layer:
//   5. gemm xl = x@Wl+bl ; xr = x@Wr+br      (fp32, A-tile in LDS)
//   6. edge_logits: wave/edge, logits = att . leakyrelu(xl[s]+xr[d]+ea@We)
//   7. node_kernel: wave/node, segment softmax + sum alpha*xl[src] (+bias,+ELU)
//   then:
//   8. aa = h2@Wm1[:64] ; bb = h2@Wm1[64:]+bm1   (edge-MLP folded to node level)
//   9. edge_mlp: out[e] = relu(aa[s]+bb[d]) . Wm2 + bm2
// ---------------------------------------------------------------------------

__device__ __forceinline__ float wave_sum(float v) {
#pragma unroll
  for (int o = 32; o > 0; o >>= 1) v += __shfl_xor(v, o, 64);
  return v;
}
__device__ __forceinline__ float wave_max(float v) {
#pragma unroll
  for (int o = 32; o > 0; o >>= 1) v = fmaxf(v, __shfl_xor(v, o, 64));
  return v;
}

__global__ __launch_bounds__(256) void degree_kernel(
    const int* __restrict__ dst, const float* __restrict__ edge_attr,
    int* __restrict__ cnt, float* __restrict__ loop_sum, int E) {
  int i = blockIdx.x * 256 + threadIdx.x;
  if (i >= E * 16) return;
  int e = i >> 4, k = i & 15;
  int d = dst[e];
  if (k == 0) atomicAdd(&cnt[d], 1);
  atomicAdd(&loop_sum[(size_t)d * 16 + k], edge_attr[i]);
}

__global__ __launch_bounds__(256) void loop_attr_kernel(
    const int* __restrict__ cnt, float* __restrict__ loop_sum, int Nn) {
  int i = blockIdx.x * 256 + threadIdx.x;
  if (i >= Nn * 16) return;
  float c = fmaxf((float)cnt[i >> 4], 1.f);
  loop_sum[i] = loop_sum[i] / c;
}

__global__ __launch_bounds__(1024) void scan_kernel(
    const int* __restrict__ cnt, int* __restrict__ rowptr,
    int* __restrict__ cursor, int Nn) {
  __shared__ int part[1024];
  int t = threadIdx.x;
  int chunk = (Nn + 1023) / 1024;
  int lo = t * chunk, hi = min(lo + chunk, Nn);
  int s = 0;
  for (int i = lo; i < hi; i++) s += cnt[i] + 1;  // +1 self loop
  part[t] = s;
  __syncthreads();
  for (int o = 1; o < 1024; o <<= 1) {
    int v = (t >= o) ? part[t - o] : 0;
    __syncthreads();
    part[t] += v;
    __syncthreads();
  }
  int run = (t == 0) ? 0 : part[t - 1];
  for (int i = lo; i < hi; i++) {
    rowptr[i] = run;
    cursor[i] = run;
    run += cnt[i] + 1;
  }
  if (t == 1023) rowptr[Nn] = part[1023];
}

__global__ __launch_bounds__(256) void csr_build_kernel(
    const int* __restrict__ src, const int* __restrict__ dst,
    int* __restrict__ cursor, int* __restrict__ eperm,
    int* __restrict__ sperm, int* __restrict__ dperm, int E, int Et) {
  int e = blockIdx.x * 256 + threadIdx.x;
  if (e >= Et) return;
  int s, d;
  if (e < E) { s = src[e]; d = dst[e]; }
  else { s = e - E; d = s; }
  int pos = atomicAdd(&cursor[d], 1);
  eperm[pos] = e;
  sperm[pos] = s;
  dperm[pos] = d;
}

// C[M,NC] = A[M,K] @ W[K,NC] (+ bias). A-tile staged in LDS, W via L1/L2.
template <int K, int NC>
__global__ __launch_bounds__(256) void gemm_kernel(
    const float* __restrict__ A, const float* __restrict__ W,
    const float* __restrict__ bias, float* __restrict__ C, int M) {
  const int ROWS = 32;
  __shared__ float Alds[ROWS * K];
  int row0 = blockIdx.x * ROWS;
  for (int i = threadIdx.x; i < ROWS * K; i += 256) {
    int r = row0 + i / K;
    Alds[i] = (r < M) ? A[(size_t)r * K + (i % K)] : 0.f;
  }
  __syncthreads();
  int col = threadIdx.x % NC;
  int rg = threadIdx.x / NC;
  const int RSTEP = 256 / NC;
  float b = bias ? bias[col] : 0.f;
  for (int r = rg; r < ROWS; r += RSTEP) {
    if (row0 + r >= M) break;
    float acc = b;
#pragma unroll 8
    for (int k = 0; k < K; k++)
      acc = fmaf(Alds[r * K + k], W[k * NC + col], acc);
    C[(size_t)(row0 + r) * NC + col] = acc;
  }
}

// One wave per CSR edge slot j. lane l covers flat channel l (head0) and
// l+64 (head1, H==2). logits[j][h] = sum_c att[h][c]*leakyrelu(m[h][c]).
template <int H>
__global__ __launch_bounds__(256) void edge_logits_kernel(
    const int* __restrict__ eperm, const int* __restrict__ sperm,
    const int* __restrict__ dperm, const float* __restrict__ edge_attr,
    const float* __restrict__ loop_attr, const float* __restrict__ We,
    const float* __restrict__ att, const float* __restrict__ xl,
    const float* __restrict__ xr, float* __restrict__ logits, int Et, int E) {
  const int HC = H * 64;
  __shared__ float WeLds[16 * 64 * H];
  for (int i = threadIdx.x; i < 16 * HC; i += 256) WeLds[i] = We[i];
  __syncthreads();
  int wid = blockIdx.x * 4 + (threadIdx.x >> 6);
  if (wid >= Et) return;
  int l = threadIdx.x & 63;
  int e = eperm[wid], s = sperm[wid], d = dperm[wid];
  const float* ea =
      (e < E) ? (edge_attr + (size_t)e * 16) : (loop_attr + (size_t)(e - E) * 16);
  float ea0 = 0.f, ea1 = 0.f;
#pragma unroll
  for (int k = 0; k < 16; k++) {
    float a = ea[k];
    ea0 = fmaf(a, WeLds[k * HC + l], ea0);
    if (H == 2) ea1 = fmaf(a, WeLds[k * HC + 64 + l], ea1);
  }
  float m0 = xl[(size_t)s * HC + l] + xr[(size_t)d * HC + l] + ea0;
  m0 = (m0 >= 0.f) ? m0 : 0.2f * m0;  // LeakyReLU(0.2)
  float p0 = att[l] * m0;
  float p1 = 0.f;
  if (H == 2) {
    float m1 = xl[(size_t)s * HC + 64 + l] + xr[(size_t)d * HC + 64 + l] + ea1;
    m1 = (m1 >= 0.f) ? m1 : 0.2f * m1;
    p1 = att[64 + l] * m1;
  }
  p0 = wave_sum(p0);
  if (H == 2) p1 = wave_sum(p1);
  if (l == 0) {
    if (H == 2) {
      float2 v = make_float2(p0, p1);
      *(float2*)(logits + (size_t)wid * 2) = v;
    } else {
      logits[wid] = p0;
    }
  }
}

// One wave per node: segment softmax over its CSR range + weighted gather-sum.
template <int H, int ELU>
__global__ __launch_bounds__(256) void node_kernel(
    const int* __restrict__ rowptr, const int* __restrict__ sperm,
    const float* __restrict__ logits, const float* __restrict__ xl,
    const float* __restrict__ bias, float* __restrict__ out, int Nn) {
  int wid = blockIdx.x * 4 + (threadIdx.x >> 6);
  if (wid >= Nn) return;
  int l = threadIdx.x & 63;
  int start = rowptr[wid], end = rowptr[wid + 1];
  float mx0 = -1e30f, mx1 = -1e30f;
  for (int j = start + l; j < end; j += 64) {
    if (H == 2) {
      float2 lg = *(const float2*)(logits + (size_t)j * 2);
      mx0 = fmaxf(mx0, lg.x);
      mx1 = fmaxf(mx1, lg.y);
    } else {
      mx0 = fmaxf(mx0, logits[j]);
    }
  }
  mx0 = wave_max(mx0);
  if (H == 2) mx1 = wave_max(mx1);
  float s0 = 0.f, s1 = 0.f;
  for (int j = start + l; j < end; j += 64) {
    if (H == 2) {
      float2 lg = *(const float2*)(logits + (size_t)j * 2);
      s0 += __expf(lg.x - mx0);
      s1 += __expf(lg.y - mx1);
    } else {
      s0 += __expf(logits[j] - mx0);
    }
  }
  s0 = wave_sum(s0);
  if (H == 2) s1 = wave_sum(s1);
  float inv0 = 1.f / s0, inv1 = (H == 2) ? 1.f / s1 : 0.f;
  float acc0 = 0.f, acc1 = 0.f;
  for (int j = start; j < end; j++) {
    int s = sperm[j];
    if (H == 2) {
      float2 lg = *(const float2*)(logits + (size_t)j * 2);
      float a0 = __expf(lg.x - mx0) * inv0;
      float a1 = __expf(lg.y - mx1) * inv1;
      acc0 = fmaf(a0, xl[(size_t)s * 128 + l], acc0);
      acc1 = fmaf(a1, xl[(size_t)s * 128 + 64 + l], acc1);
    } else {
      float a0 = __expf(logits[j] - mx0) * inv0;
      acc0 = fmaf(a0, xl[(size_t)s * 64 + l], acc0);
    }
  }
  if (H == 2) {
    float v0 = acc0 + bias[l], v1 = acc1 + bias[64 + l];
    if (ELU) {
      v0 = (v0 > 0.f) ? v0 : expm1f(v0);
      v1 = (v1 > 0.f) ? v1 : expm1f(v1);
    }
    out[(size_t)wid * 128 + l] = v0;
    out[(size_t)wid * 128 + 64 + l] = v1;
  } else {
    out[(size_t)wid * 64 + l] = acc0 + bias[l];
  }
}

// One wave per original edge: out[e] = relu(aa[s]+bb[d]) . Wm2 + bm2
__global__ __launch_bounds__(256) void edge_mlp_kernel(
    const int* __restrict__ src, const int* __restrict__ dst,
    const float* __restrict__ aa, const float* __restrict__ bb,
    const float* __restrict__ Wm2, const float* __restrict__ bm2,
    float* __restrict__ out, int E) {
  int wid = blockIdx.x * 4 + (threadIdx.x >> 6);
  if (wid >= E) return;
  int l = threadIdx.x & 63;
  int s = src[wid], d = dst[wid];
  float z = aa[(size_t)s * 64 + l] + bb[(size_t)d * 64 + l];
  z = fmaxf(z, 0.f);
  float p = z * Wm2[l];
  p = wave_sum(p);
  if (l == 0) out[wid] = p + bm2[0];
}

extern "C" void kernel_launch(void* const* d_in, const int* in_sizes, int n_in,
                              void* d_out, int out_size, void* d_ws,
                              size_t ws_size, hipStream_t stream) {
  const float* x = (const float*)d_in[0];
  const int* ei = (const int*)d_in[1];
  const float* edge_attr = (const float*)d_in[2];
  const float* Wl1 = (const float*)d_in[3];
  const float* bl1 = (const float*)d_in[4];
  const float* Wr1 = (const float*)d_in[5];
  const float* br1 = (const float*)d_in[6];
  const float* We1 = (const float*)d_in[7];
  const float* att1 = (const float*)d_in[8];
  const float* b1 = (const float*)d_in[9];
  const float* Wl2 = (const float*)d_in[10];
  const float* bl2 = (const float*)d_in[11];
  const float* Wr2 = (const float*)d_in[12];
  const float* br2 = (const float*)d_in[13];
  const float* We2 = (const float*)d_in[14];
  const float* att2 = (const float*)d_in[15];
  const float* b2 = (const float*)d_in[16];
  const float* Wm1 = (const float*)d_in[17];
  const float* bm1 = (const float*)d_in[18];
  const float* Wm2 = (const float*)d_in[19];
  const float* bm2 = (const float*)d_in[20];

  const int Nn = in_sizes[0] / 128;  // 50000
  const int E = in_sizes[1] / 2;     // 800000
  const int Et = E + Nn;             // 850000
  const int* src = ei;
  const int* dst = ei + E;

  char* ws = (char*)d_ws;
  size_t off = 0;
  auto alloc = [&](size_t bytes) -> char* {
    char* p = ws + off;
    off += (bytes + 255) & ~(size_t)255;
    return p;
  };
  int* cnt = (int*)alloc((size_t)Nn * 4);
  float* loop_sum = (float*)alloc((size_t)Nn * 16 * 4);  // becomes loop_attr
  int* rowptr = (int*)alloc((size_t)(Nn + 1) * 4);
  int* cursor = (int*)alloc((size_t)Nn * 4);
  int* eperm = (int*)alloc((size_t)Et * 4);
  int* sperm = (int*)alloc((size_t)Et * 4);
  int* dperm = (int*)alloc((size_t)Et * 4);
  float* xl = (float*)alloc((size_t)Nn * 128 * 4);
  float* xr = (float*)alloc((size_t)Nn * 128 * 4);
  float* logits = (float*)alloc((size_t)Et * 2 * 4);
  float* h1 = (float*)alloc((size_t)Nn * 128 * 4);
  float* h2 = (float*)alloc((size_t)Nn * 64 * 4);
  float* aa = xl;  // reuse after layer-2 node pass
  float* bb = xr;

  hipMemsetAsync(cnt, 0, (size_t)Nn * 4, stream);
  hipMemsetAsync(loop_sum, 0, (size_t)Nn * 16 * 4, stream);

  // --- graph preprocessing ---
  {
    int total = E * 16;
    degree_kernel<<<(total + 255) / 256, 256, 0, stream>>>(dst, edge_attr, cnt,
                                                           loop_sum, E);
  }
  loop_attr_kernel<<<(Nn * 16 + 255) / 256, 256, 0, stream>>>(cnt, loop_sum, Nn);
  scan_kernel<<<1, 1024, 0, stream>>>(cnt, rowptr, cursor, Nn);
  csr_build_kernel<<<(Et + 255) / 256, 256, 0, stream>>>(src, dst, cursor, eperm,
                                                         sperm, dperm, E, Et);

  // --- layer 1 (heads=2, hid=64) ---
  gemm_kernel<128, 128><<<(Nn + 31) / 32, 256, 0, stream>>>(x, Wl1, bl1, xl, Nn);
  gemm_kernel<128, 128><<<(Nn + 31) / 32, 256, 0, stream>>>(x, Wr1, br1, xr, Nn);
  edge_logits_kernel<2><<<(Et + 3) / 4, 256, 0, stream>>>(
      eperm, sperm, dperm, edge_attr, loop_sum, We1, att1, xl, xr, logits, Et, E);
  node_kernel<2, 1><<<(Nn + 3) / 4, 256, 0, stream>>>(rowptr, sperm, logits, xl,
                                                      b1, h1, Nn);

  // --- layer 2 (heads=1, out=64) ---
  gemm_kernel<128, 64><<<(Nn + 31) / 32, 256, 0, stream>>>(h1, Wl2, bl2, xl, Nn);
  gemm_kernel<128, 64><<<(Nn + 31) / 32, 256, 0, stream>>>(h1, Wr2, br2, xr, Nn);
  edge_logits_kernel<1><<<(Et + 3) / 4, 256, 0, stream>>>(
      eperm, sperm, dperm, edge_attr, loop_sum, We2, att2, xl, xr, logits, Et, E);
  node_kernel<1, 0><<<(Nn + 3) / 4, 256, 0, stream>>>(rowptr, sperm, logits, xl,
                                                      b2, h2, Nn);

  // --- edge MLP, folded: z = relu(h2[s]@Wm1_top + h2[d]@Wm1_bot + bm1) ---
  gemm_kernel<64, 64><<<(Nn + 31) / 32, 256, 0, stream>>>(h2, Wm1, nullptr, aa, Nn);
  gemm_kernel<64, 64><<<(Nn + 31) / 32, 256, 0, stream>>>(h2, Wm1 + 64 * 64, bm1,
                                                          bb, Nn);
  edge_mlp_kernel<<<(E + 3) / 4, 256, 0, stream>>>(src, dst, aa, bb, Wm2, bm2,
                                                   (float*)d_out, E);
}

// Round 4
// 920.843 us; speedup vs baseline: 1.9756x; 1.9756x over previous
//
#include <hip/hip_runtime.h>
#include <cstdint>
#include <cstddef>

// ---------------------------------------------------------------------------
// GATv2 edge predictor, fp32 throughout.
//   1. cnt_kernel: cnt[dst]++                      (1 atomic per edge)
//   2. scan_kernel: rowptr = exscan(cnt+1)         (single block)
//   3. csr_build: scatter edge ids by dst -> eperm/sperm
//   4. loop_attr_kernel: self-loop attr = mean of incoming edge_attr (gather)
//   per GAT layer:
//   5. gemm xl = x@Wl+bl ; xr = x@Wr+br            (reg-blocked fp32)
//   6. node_fused: one wave/node, ONLINE softmax:
//        per edge: eaW from reg-held We cols, logit = att.lrelu(xl[s]+xr[d]+eaW)
//        online max/sum/acc update; final acc/s + bias (+ELU)
//   then: aa = h2@Wm1_top ; bb = h2@Wm1_bot + bm1  (edge MLP folded to nodes)
//   7. edge_mlp: 4 edges/wave, out[e] = relu(aa[s]+bb[d]).Wm2 + bm2
// ---------------------------------------------------------------------------

__device__ __forceinline__ float wave_sum(float v) {
#pragma unroll
  for (int o = 32; o > 0; o >>= 1) v += __shfl_xor(v, o, 64);
  return v;
}
// two independent reductions with interleaved shuffle chains (hides lgkm latency)
__device__ __forceinline__ void wave_sum2(float& a, float& b) {
#pragma unroll
  for (int o = 32; o > 0; o >>= 1) {
    float ta = __shfl_xor(a, o, 64);
    float tb = __shfl_xor(b, o, 64);
    a += ta;
    b += tb;
  }
}

__global__ __launch_bounds__(256) void cnt_kernel(const int* __restrict__ dst,
                                                  int* __restrict__ cnt, int E) {
  int e = blockIdx.x * 256 + threadIdx.x;
  if (e < E) atomicAdd(&cnt[dst[e]], 1);
}

__global__ __launch_bounds__(1024) void scan_kernel(
    const int* __restrict__ cnt, int* __restrict__ rowptr,
    int* __restrict__ cursor, int Nn) {
  __shared__ int part[1024];
  int t = threadIdx.x;
  int chunk = (Nn + 1023) / 1024;
  int lo = t * chunk, hi = min(lo + chunk, Nn);
  int s = 0;
  for (int i = lo; i < hi; i++) s += cnt[i] + 1;  // +1 self loop
  part[t] = s;
  __syncthreads();
  for (int o = 1; o < 1024; o <<= 1) {
    int v = (t >= o) ? part[t - o] : 0;
    __syncthreads();
    part[t] += v;
    __syncthreads();
  }
  int run = (t == 0) ? 0 : part[t - 1];
  for (int i = lo; i < hi; i++) {
    rowptr[i] = run;
    cursor[i] = run;
    run += cnt[i] + 1;
  }
  if (t == 1023) rowptr[Nn] = part[1023];
}

__global__ __launch_bounds__(256) void csr_build_kernel(
    const int* __restrict__ src, const int* __restrict__ dst,
    int* __restrict__ cursor, int* __restrict__ eperm,
    int* __restrict__ sperm, int E, int Et) {
  int e = blockIdx.x * 256 + threadIdx.x;
  if (e >= Et) return;
  int s, d;
  if (e < E) { s = src[e]; d = dst[e]; }
  else { s = e - E; d = s; }
  int pos = atomicAdd(&cursor[d], 1);
  eperm[pos] = e;
  sperm[pos] = s;
}

// self-loop attr (fill='mean'): wave/node, 4 edge-slots x 16 dims per wave
__global__ __launch_bounds__(256) void loop_attr_kernel(
    const int* __restrict__ rowptr, const int* __restrict__ eperm,
    const float* __restrict__ edge_attr, float* __restrict__ loop_attr,
    int Nn, int E) {
  int wid = blockIdx.x * 4 + (threadIdx.x >> 6);
  if (wid >= Nn) return;
  int l = threadIdx.x & 63;
  int sub = l >> 4, kk = l & 15;
  int start = rowptr[wid], end = rowptr[wid + 1];
  float acc = 0.f;
  for (int j = start + sub; j < end; j += 4) {
    int e = eperm[j];
    if (e < E) acc += edge_attr[(size_t)e * 16 + kk];
  }
  acc += __shfl_xor(acc, 16, 64);
  acc += __shfl_xor(acc, 32, 64);
  if (sub == 0) {
    float c = fmaxf((float)(end - start - 1), 1.f);
    loop_attr[(size_t)wid * 16 + kk] = acc / c;
  }
}

// C[M,NC] = A[M,K] @ W[K,NC] (+bias). 64-row tile in LDS; each thread owns
// RP rows x 4 cols (float4 on W and C).
template <int K, int NC>
__global__ __launch_bounds__(256) void gemm_kernel(
    const float* __restrict__ A, const float* __restrict__ W,
    const float* __restrict__ bias, float* __restrict__ C, int M) {
  const int BM = 64;
  const int CQ = NC / 4;    // col quads per row
  const int RP = BM / (256 / CQ);  // rows per thread
  __shared__ float Alds[BM * K];
  int row0 = blockIdx.x * BM;
  for (int i = threadIdx.x; i < BM * K / 4; i += 256) {
    int r = i / (K / 4);
    float4 v = make_float4(0.f, 0.f, 0.f, 0.f);
    if (row0 + r < M) v = ((const float4*)A)[(size_t)(row0 + r) * (K / 4) + (i % (K / 4))];
    ((float4*)Alds)[i] = v;
  }
  __syncthreads();
  int cq = threadIdx.x % CQ;
  int rg = threadIdx.x / CQ;
  float4 acc[RP];
#pragma unroll
  for (int r = 0; r < RP; r++) acc[r] = make_float4(0.f, 0.f, 0.f, 0.f);
  const float4* W4 = (const float4*)W;
  for (int k = 0; k < K; k += 4) {
    float4 w0 = W4[(size_t)(k + 0) * CQ + cq];
    float4 w1 = W4[(size_t)(k + 1) * CQ + cq];
    float4 w2 = W4[(size_t)(k + 2) * CQ + cq];
    float4 w3 = W4[(size_t)(k + 3) * CQ + cq];
#pragma unroll
    for (int r = 0; r < RP; r++) {
      float4 a = ((const float4*)Alds)[(rg * RP + r) * (K / 4) + (k >> 2)];
      acc[r].x = fmaf(a.x, w0.x, acc[r].x);
      acc[r].y = fmaf(a.x, w0.y, acc[r].y);
      acc[r].z = fmaf(a.x, w0.z, acc[r].z);
      acc[r].w = fmaf(a.x, w0.w, acc[r].w);
      acc[r].x = fmaf(a.y, w1.x, acc[r].x);
      acc[r].y = fmaf(a.y, w1.y, acc[r].y);
      acc[r].z = fmaf(a.y, w1.z, acc[r].z);
      acc[r].w = fmaf(a.y, w1.w, acc[r].w);
      acc[r].x = fmaf(a.z, w2.x, acc[r].x);
      acc[r].y = fmaf(a.z, w2.y, acc[r].y);
      acc[r].z = fmaf(a.z, w2.z, acc[r].z);
      acc[r].w = fmaf(a.z, w2.w, acc[r].w);
      acc[r].x = fmaf(a.w, w3.x, acc[r].x);
      acc[r].y = fmaf(a.w, w3.y, acc[r].y);
      acc[r].z = fmaf(a.w, w3.z, acc[r].z);
      acc[r].w = fmaf(a.w, w3.w, acc[r].w);
    }
  }
  float4 b4 = bias ? ((const float4*)bias)[cq] : make_float4(0.f, 0.f, 0.f, 0.f);
#pragma unroll
  for (int r = 0; r < RP; r++) {
    int row = row0 + rg * RP + r;
    if (row < M) {
      float4 o = make_float4(acc[r].x + b4.x, acc[r].y + b4.y,
                             acc[r].z + b4.z, acc[r].w + b4.w);
      ((float4*)C)[(size_t)row * CQ + cq] = o;
    }
  }
}

// Fused per-node GATv2: logits + online segment softmax + aggregation.
// One wave per node; lane l = channel l (head0) and l+64 (head1 if H==2).
template <int H, int ELU>
__global__ __launch_bounds__(256) void node_fused_kernel(
    const int* __restrict__ rowptr, const int* __restrict__ eperm,
    const int* __restrict__ sperm, const float* __restrict__ edge_attr,
    const float* __restrict__ loop_attr, const float* __restrict__ We,
    const float* __restrict__ att, const float* __restrict__ xl,
    const float* __restrict__ xr, const float* __restrict__ bias,
    float* __restrict__ out, int Nn, int E) {
  const int HC = H * 64;
  int wid = blockIdx.x * 4 + (threadIdx.x >> 6);
  if (wid >= Nn) return;
  int l = threadIdx.x & 63;
  // hoist this lane's We column(s) into registers (reused for every edge)
  float we0[16], we1[16];
#pragma unroll
  for (int k = 0; k < 16; k++) {
    we0[k] = We[k * HC + l];
    if (H == 2) we1[k] = We[k * HC + 64 + l];
  }
  float xr0 = xr[(size_t)wid * HC + l];
  float xr1 = (H == 2) ? xr[(size_t)wid * HC + 64 + l] : 0.f;
  float a0 = att[l];
  float a1 = (H == 2) ? att[64 + l] : 0.f;
  int start = rowptr[wid], end = rowptr[wid + 1];
  float m0 = -1e30f, m1 = -1e30f;
  float s0 = 0.f, s1 = 0.f, acc0 = 0.f, acc1 = 0.f;
  for (int j = start; j < end; j++) {
    int e = eperm[j];
    int s = sperm[j];
    const float4* ea4 = (const float4*)((e < E)
                            ? (edge_attr + (size_t)e * 16)
                            : (loop_attr + (size_t)(e - E) * 16));
    float4 c0 = ea4[0], c1 = ea4[1], c2 = ea4[2], c3 = ea4[3];
    float xls0 = xl[(size_t)s * HC + l];
    float xls1 = (H == 2) ? xl[(size_t)s * HC + 64 + l] : 0.f;
    float eav[16] = {c0.x, c0.y, c0.z, c0.w, c1.x, c1.y, c1.z, c1.w,
                     c2.x, c2.y, c2.z, c2.w, c3.x, c3.y, c3.z, c3.w};
    float ea0 = 0.f, ea1 = 0.f;
#pragma unroll
    for (int k = 0; k < 16; k++) ea0 = fmaf(eav[k], we0[k], ea0);
    if (H == 2) {
#pragma unroll
      for (int k = 0; k < 16; k++) ea1 = fmaf(eav[k], we1[k], ea1);
    }
    float mm0 = xls0 + xr0 + ea0;
    mm0 = (mm0 >= 0.f) ? mm0 : 0.2f * mm0;  // LeakyReLU(0.2)
    float p0 = a0 * mm0;
    float p1 = 0.f;
    if (H == 2) {
      float mm1 = xls1 + xr1 + ea1;
      mm1 = (mm1 >= 0.f) ? mm1 : 0.2f * mm1;
      p1 = a1 * mm1;
      wave_sum2(p0, p1);
    } else {
      p0 = wave_sum(p0);
    }
    // online softmax update, head 0
    float nm0 = fmaxf(m0, p0);
    float r0 = __expf(m0 - nm0);
    float e0 = __expf(p0 - nm0);
    s0 = fmaf(s0, r0, e0);
    acc0 = fmaf(acc0, r0, e0 * xls0);
    m0 = nm0;
    if (H == 2) {
      float nm1 = fmaxf(m1, p1);
      float r1 = __expf(m1 - nm1);
      float e1 = __expf(p1 - nm1);
      s1 = fmaf(s1, r1, e1);
      acc1 = fmaf(acc1, r1, e1 * xls1);
      m1 = nm1;
    }
  }
  if (H == 2) {
    float v0 = acc0 / s0 + bias[l];
    float v1 = acc1 / s1 + bias[64 + l];
    if (ELU) {
      v0 = (v0 > 0.f) ? v0 : expm1f(v0);
      v1 = (v1 > 0.f) ? v1 : expm1f(v1);
    }
    out[(size_t)wid * 128 + l] = v0;
    out[(size_t)wid * 128 + 64 + l] = v1;
  } else {
    out[(size_t)wid * 64 + l] = acc0 / s0 + bias[l];
  }
}

// 4 edges per wave; 16 lanes x float4 per edge.
__global__ __launch_bounds__(256) void edge_mlp_kernel(
    const int* __restrict__ src, const int* __restrict__ dst,
    const float* __restrict__ aa, const float* __restrict__ bb,
    const float* __restrict__ Wm2, const float* __restrict__ bm2,
    float* __restrict__ out, int E) {
  int t = blockIdx.x * 256 + threadIdx.x;
  int eid = t >> 4;
  if (eid >= E) return;
  int g = threadIdx.x & 15;
  float4 w = ((const float4*)Wm2)[g];
  int s = src[eid], d = dst[eid];
  float4 za = ((const float4*)aa)[(size_t)s * 16 + g];
  float4 zb = ((const float4*)bb)[(size_t)d * 16 + g];
  float p = fmaxf(za.x + zb.x, 0.f) * w.x;
  p = fmaf(fmaxf(za.y + zb.y, 0.f), w.y, p);
  p = fmaf(fmaxf(za.z + zb.z, 0.f), w.z, p);
  p = fmaf(fmaxf(za.w + zb.w, 0.f), w.w, p);
#pragma unroll
  for (int o = 8; o > 0; o >>= 1) p += __shfl_xor(p, o, 64);
  if (g == 0) out[eid] = p + bm2[0];
}

extern "C" void kernel_launch(void* const* d_in, const int* in_sizes, int n_in,
                              void* d_out, int out_size, void* d_ws,
                              size_t ws_size, hipStream_t stream) {
  const float* x = (const float*)d_in[0];
  const int* ei = (const int*)d_in[1];
  const float* edge_attr = (const float*)d_in[2];
  const float* Wl1 = (const float*)d_in[3];
  const float* bl1 = (const float*)d_in[4];
  const float* Wr1 = (const float*)d_in[5];
  const float* br1 = (const float*)d_in[6];
  const float* We1 = (const float*)d_in[7];
  const float* att1 = (const float*)d_in[8];
  const float* b1 = (const float*)d_in[9];
  const float* Wl2 = (const float*)d_in[10];
  const float* bl2 = (const float*)d_in[11];
  const float* Wr2 = (const float*)d_in[12];
  const float* br2 = (const float*)d_in[13];
  const float* We2 = (const float*)d_in[14];
  const float* att2 = (const float*)d_in[15];
  const float* b2 = (const float*)d_in[16];
  const float* Wm1 = (const float*)d_in[17];
  const float* bm1 = (const float*)d_in[18];
  const float* Wm2 = (const float*)d_in[19];
  const float* bm2 = (const float*)d_in[20];

  const int Nn = in_sizes[0] / 128;  // 50000
  const int E = in_sizes[1] / 2;     // 800000
  const int Et = E + Nn;             // 850000
  const int* src = ei;
  const int* dst = ei + E;

  char* ws = (char*)d_ws;
  size_t off = 0;
  auto alloc = [&](size_t bytes) -> char* {
    char* p = ws + off;
    off += (bytes + 255) & ~(size_t)255;
    return p;
  };
  int* cnt = (int*)alloc((size_t)Nn * 4);
  float* loop_attr = (float*)alloc((size_t)Nn * 16 * 4);
  int* rowptr = (int*)alloc((size_t)(Nn + 1) * 4);
  int* cursor = (int*)alloc((size_t)Nn * 4);
  int* eperm = (int*)alloc((size_t)Et * 4);
  int* sperm = (int*)alloc((size_t)Et * 4);
  float* xl = (float*)alloc((size_t)Nn * 128 * 4);
  float* xr = (float*)alloc((size_t)Nn * 128 * 4);
  float* h1 = (float*)alloc((size_t)Nn * 128 * 4);
  float* h2 = (float*)alloc((size_t)Nn * 64 * 4);
  float* aa = xl;  // reuse after layer-2 node pass
  float* bb = xr;

  hipMemsetAsync(cnt, 0, (size_t)Nn * 4, stream);

  // --- graph preprocessing ---
  cnt_kernel<<<(E + 255) / 256, 256, 0, stream>>>(dst, cnt, E);
  scan_kernel<<<1, 1024, 0, stream>>>(cnt, rowptr, cursor, Nn);
  csr_build_kernel<<<(Et + 255) / 256, 256, 0, stream>>>(src, dst, cursor, eperm,
                                                         sperm, E, Et);
  loop_attr_kernel<<<(Nn + 3) / 4, 256, 0, stream>>>(rowptr, eperm, edge_attr,
                                                     loop_attr, Nn, E);

  // --- layer 1 (heads=2, hid=64) ---
  gemm_kernel<128, 128><<<(Nn + 63) / 64, 256, 0, stream>>>(x, Wl1, bl1, xl, Nn);
  gemm_kernel<128, 128><<<(Nn + 63) / 64, 256, 0, stream>>>(x, Wr1, br1, xr, Nn);
  node_fused_kernel<2, 1><<<(Nn + 3) / 4, 256, 0, stream>>>(
      rowptr, eperm, sperm, edge_attr, loop_attr, We1, att1, xl, xr, b1, h1, Nn, E);

  // --- layer 2 (heads=1, out=64) ---
  gemm_kernel<128, 64><<<(Nn + 63) / 64, 256, 0, stream>>>(h1, Wl2, bl2, xl, Nn);
  gemm_kernel<128, 64><<<(Nn + 63) / 64, 256, 0, stream>>>(h1, Wr2, br2, xr, Nn);
  node_fused_kernel<1, 0><<<(Nn + 3) / 4, 256, 0, stream>>>(
      rowptr, eperm, sperm, edge_attr, loop_attr, We2, att2, xl, xr, b2, h2, Nn, E);

  // --- edge MLP, folded: z = relu(h2[s]@Wm1_top + h2[d]@Wm1_bot + bm1) ---
  gemm_kernel<64, 64><<<(Nn + 63) / 64, 256, 0, stream>>>(h2, Wm1, nullptr, aa, Nn);
  gemm_kernel<64, 64><<<(Nn + 63) / 64, 256, 0, stream>>>(h2, Wm1 + 64 * 64, bm1,
                                                          bb, Nn);
  edge_mlp_kernel<<<(E * 16 + 255) / 256, 256, 0, stream>>>(src, dst, aa, bb,
                                                            Wm2, bm2,
                                                            (float*)d_out, E);
}

// Round 6
// 798.037 us; speedup vs baseline: 2.2796x; 1.1539x over previous
//
#include <hip/hip_runtime.h>
#include <cstdint>
#include <cstddef>

// ---------------------------------------------------------------------------
// GATv2 edge predictor, fp32 throughout.
//   preprocessing: cnt -> scan -> csr_build -> loop_attr (mean fill)
//   per GAT layer:
//     gemm xl = x@Wl+bl ; xr = x@Wr+br          (reg-blocked fp32)
//     node_fused{2,1}: one wave/node, ONLINE softmax, half-wave mapping:
//       H=2: lanes 0-31 head0 (float2 ch/lane), lanes 32-63 head1
//       H=1: lanes 0-31 edge j, lanes 32-63 edge j+1; merge states at end
//       2-deep pipeline: idx prefetch j+2, data prefetch j+1 (named regs)
//       readfirstlane bounds -> uniform idx/ea loads (scalar cache)
//   then: aa = h2@Wm1_top ; bb = h2@Wm1_bot+bm1 (edge MLP folded to nodes)
//   edge_mlp: 4 edges/wave, out[e] = relu(aa[s]+bb[d]).Wm2 + bm2
// ---------------------------------------------------------------------------

__device__ __forceinline__ float half_sum(float v) {
#pragma unroll
  for (int o = 1; o <= 16; o <<= 1) v += __shfl_xor(v, o, 64);
  return v;
}

__global__ __launch_bounds__(256) void cnt_kernel(const int* __restrict__ dst,
                                                  int* __restrict__ cnt, int E) {
  int e = blockIdx.x * 256 + threadIdx.x;
  if (e < E) atomicAdd(&cnt[dst[e]], 1);
}

__global__ __launch_bounds__(1024) void scan_kernel(
    const int* __restrict__ cnt, int* __restrict__ rowptr,
    int* __restrict__ cursor, int Nn) {
  __shared__ int part[1024];
  int t = threadIdx.x;
  int chunk = (Nn + 1023) / 1024;
  int lo = t * chunk, hi = min(lo + chunk, Nn);
  int s = 0;
  for (int i = lo; i < hi; i++) s += cnt[i] + 1;  // +1 self loop
  part[t] = s;
  __syncthreads();
  for (int o = 1; o < 1024; o <<= 1) {
    int v = (t >= o) ? part[t - o] : 0;
    __syncthreads();
    part[t] += v;
    __syncthreads();
  }
  int run = (t == 0) ? 0 : part[t - 1];
  for (int i = lo; i < hi; i++) {
    rowptr[i] = run;
    cursor[i] = run;
    run += cnt[i] + 1;
  }
  if (t == 1023) rowptr[Nn] = part[1023];
}

__global__ __launch_bounds__(256) void csr_build_kernel(
    const int* __restrict__ src, const int* __restrict__ dst,
    int* __restrict__ cursor, int* __restrict__ eperm,
    int* __restrict__ sperm, int E, int Et) {
  int e = blockIdx.x * 256 + threadIdx.x;
  if (e >= Et) return;
  int s, d;
  if (e < E) { s = src[e]; d = dst[e]; }
  else { s = e - E; d = s; }
  int pos = atomicAdd(&cursor[d], 1);
  eperm[pos] = e;
  sperm[pos] = s;
}

// self-loop attr (fill='mean'): wave/node, 4 edge-slots x 16 dims per wave
__global__ __launch_bounds__(256) void loop_attr_kernel(
    const int* __restrict__ rowptr, const int* __restrict__ eperm,
    const float* __restrict__ edge_attr, float* __restrict__ loop_attr,
    int Nn, int E) {
  int wid = blockIdx.x * 4 + (threadIdx.x >> 6);
  if (wid >= Nn) return;
  int l = threadIdx.x & 63;
  int sub = l >> 4, kk = l & 15;
  int start = rowptr[wid], end = rowptr[wid + 1];
  float acc = 0.f;
  for (int j = start + sub; j < end; j += 4) {
    int e = eperm[j];
    if (e < E) acc += edge_attr[(size_t)e * 16 + kk];
  }
  acc += __shfl_xor(acc, 16, 64);
  acc += __shfl_xor(acc, 32, 64);
  if (sub == 0) {
    float c = fmaxf((float)(end - start - 1), 1.f);
    loop_attr[(size_t)wid * 16 + kk] = acc / c;
  }
}

// C[M,NC] = A[M,K] @ W[K,NC] (+bias). 64-row tile in LDS; each thread owns
// RP rows x 4 cols (float4 on W and C).
template <int K, int NC>
__global__ __launch_bounds__(256) void gemm_kernel(
    const float* __restrict__ A, const float* __restrict__ W,
    const float* __restrict__ bias, float* __restrict__ C, int M) {
  const int BM = 64;
  const int CQ = NC / 4;           // col quads per row
  const int RP = BM / (256 / CQ);  // rows per thread
  __shared__ float Alds[BM * K];
  int row0 = blockIdx.x * BM;
  for (int i = threadIdx.x; i < BM * K / 4; i += 256) {
    int r = i / (K / 4);
    float4 v = make_float4(0.f, 0.f, 0.f, 0.f);
    if (row0 + r < M) v = ((const float4*)A)[(size_t)(row0 + r) * (K / 4) + (i % (K / 4))];
    ((float4*)Alds)[i] = v;
  }
  __syncthreads();
  int cq = threadIdx.x % CQ;
  int rg = threadIdx.x / CQ;
  float4 acc[RP];
#pragma unroll
  for (int r = 0; r < RP; r++) acc[r] = make_float4(0.f, 0.f, 0.f, 0.f);
  const float4* W4 = (const float4*)W;
  for (int k = 0; k < K; k += 4) {
    float4 w0 = W4[(size_t)(k + 0) * CQ + cq];
    float4 w1 = W4[(size_t)(k + 1) * CQ + cq];
    float4 w2 = W4[(size_t)(k + 2) * CQ + cq];
    float4 w3 = W4[(size_t)(k + 3) * CQ + cq];
#pragma unroll
    for (int r = 0; r < RP; r++) {
      float4 a = ((const float4*)Alds)[(rg * RP + r) * (K / 4) + (k >> 2)];
      acc[r].x = fmaf(a.x, w0.x, acc[r].x);
      acc[r].y = fmaf(a.x, w0.y, acc[r].y);
      acc[r].z = fmaf(a.x, w0.z, acc[r].z);
      acc[r].w = fmaf(a.x, w0.w, acc[r].w);
      acc[r].x = fmaf(a.y, w1.x, acc[r].x);
      acc[r].y = fmaf(a.y, w1.y, acc[r].y);
      acc[r].z = fmaf(a.y, w1.z, acc[r].z);
      acc[r].w = fmaf(a.y, w1.w, acc[r].w);
      acc[r].x = fmaf(a.z, w2.x, acc[r].x);
      acc[r].y = fmaf(a.z, w2.y, acc[r].y);
      acc[r].z = fmaf(a.z, w2.z, acc[r].z);
      acc[r].w = fmaf(a.z, w2.w, acc[r].w);
      acc[r].x = fmaf(a.w, w3.x, acc[r].x);
      acc[r].y = fmaf(a.w, w3.y, acc[r].y);
      acc[r].z = fmaf(a.w, w3.z, acc[r].z);
      acc[r].w = fmaf(a.w, w3.w, acc[r].w);
    }
  }
  float4 b4 = bias ? ((const float4*)bias)[cq] : make_float4(0.f, 0.f, 0.f, 0.f);
#pragma unroll
  for (int r = 0; r < RP; r++) {
    int row = row0 + rg * RP + r;
    if (row < M) {
      float4 o = make_float4(acc[r].x + b4.x, acc[r].y + b4.y,
                             acc[r].z + b4.z, acc[r].w + b4.w);
      ((float4*)C)[(size_t)row * CQ + cq] = o;
    }
  }
}

// H=2 fused node pass: lanes 0-31 = head0, lanes 32-63 = head1, float2 ch/lane.
// 5-step half-wave logit reduction; 2-deep pipelined edge loop.
template <int ELU>
__global__ __launch_bounds__(256) void node_fused2_kernel(
    const int* __restrict__ rowptr, const int* __restrict__ eperm,
    const int* __restrict__ sperm, const float* __restrict__ edge_attr,
    const float* __restrict__ loop_attr, const float* __restrict__ We,
    const float* __restrict__ att, const float* __restrict__ xl,
    const float* __restrict__ xr, const float* __restrict__ bias,
    float* __restrict__ out, int Nn, int E) {
  int wid = blockIdx.x * 4 + (threadIdx.x >> 6);
  if (wid >= Nn) return;
  int l = threadIdx.x & 63;
  int ch = ((l >> 5) << 6) | ((l & 31) << 1);  // head*64 + 2*q
  float2 we[16];
#pragma unroll
  for (int k = 0; k < 16; k++) we[k] = *(const float2*)(We + k * 128 + ch);
  float2 xr2 = *(const float2*)(xr + (size_t)wid * 128 + ch);
  float2 at2 = *(const float2*)(att + ch);
  int start = __builtin_amdgcn_readfirstlane(rowptr[wid]);
  int end = __builtin_amdgcn_readfirstlane(rowptr[wid + 1]);
  float4 A0, A1, A2, A3;
  float2 X;
  int e_n, s_n;
  {
    int e_c = eperm[start], s_c = sperm[start];
    const float4* p4 = (const float4*)((e_c < E)
                           ? edge_attr + (size_t)e_c * 16
                           : loop_attr + (size_t)(e_c - E) * 16);
    A0 = p4[0]; A1 = p4[1]; A2 = p4[2]; A3 = p4[3];
    X = *(const float2*)(xl + (size_t)s_c * 128 + ch);
    int j1 = min(start + 1, end - 1);
    e_n = eperm[j1];
    s_n = sperm[j1];
  }
  float m = -1e30f, sden = 0.f, accx = 0.f, accy = 0.f;
  for (int j = start; j < end; ++j) {
    int j2 = min(j + 2, end - 1);
    int e2 = eperm[j2], s2 = sperm[j2];
    const float4* p4 = (const float4*)((e_n < E)
                           ? edge_attr + (size_t)e_n * 16
                           : loop_attr + (size_t)(e_n - E) * 16);
    float4 B0 = p4[0], B1 = p4[1], B2 = p4[2], B3 = p4[3];
    float2 Y = *(const float2*)(xl + (size_t)s_n * 128 + ch);
    float av[16] = {A0.x, A0.y, A0.z, A0.w, A1.x, A1.y, A1.z, A1.w,
                    A2.x, A2.y, A2.z, A2.w, A3.x, A3.y, A3.z, A3.w};
    float ex = 0.f, ey = 0.f;
#pragma unroll
    for (int k = 0; k < 16; k++) {
      ex = fmaf(av[k], we[k].x, ex);
      ey = fmaf(av[k], we[k].y, ey);
    }
    float mx = X.x + xr2.x + ex;
    float my = X.y + xr2.y + ey;
    mx = (mx >= 0.f) ? mx : 0.2f * mx;  // LeakyReLU(0.2)
    my = (my >= 0.f) ? my : 0.2f * my;
    float p = half_sum(fmaf(at2.x, mx, at2.y * my));
    float nm = fmaxf(m, p);
    float r = __expf(m - nm), ep = __expf(p - nm);
    sden = fmaf(sden, r, ep);
    accx = fmaf(accx, r, ep * X.x);
    accy = fmaf(accy, r, ep * X.y);
    m = nm;
    A0 = B0; A1 = B1; A2 = B2; A3 = B3; X = Y;
    e_n = e2; s_n = s2;
  }
  float inv = 1.f / sden;
  float2 b2 = *(const float2*)(bias + ch);
  float vx = fmaf(accx, inv, b2.x);
  float vy = fmaf(accy, inv, b2.y);
  if (ELU) {
    vx = (vx > 0.f) ? vx : expm1f(vx);
    vy = (vy > 0.f) ? vy : expm1f(vy);
  }
  *(float2*)(out + (size_t)wid * 128 + ch) = make_float2(vx, vy);
}

// H=1 fused node pass: half-wave per edge (2 edges/iteration), float2 ch/lane,
// online-softmax state merge across halves at the end.
__global__ __launch_bounds__(256) void node_fused1_kernel(
    const int* __restrict__ rowptr, const int* __restrict__ eperm,
    const int* __restrict__ sperm, const float* __restrict__ edge_attr,
    const float* __restrict__ loop_attr, const float* __restrict__ We,
    const float* __restrict__ att, const float* __restrict__ xl,
    const float* __restrict__ xr, const float* __restrict__ bias,
    float* __restrict__ out, int Nn, int E) {
  int wid = blockIdx.x * 4 + (threadIdx.x >> 6);
  if (wid >= Nn) return;
  int l = threadIdx.x & 63;
  int half = l >> 5;
  int ch = (l & 31) << 1;
  float2 we[16];
#pragma unroll
  for (int k = 0; k < 16; k++) we[k] = *(const float2*)(We + k * 64 + ch);
  float2 xr2 = *(const float2*)(xr + (size_t)wid * 64 + ch);
  float2 at2 = *(const float2*)(att + ch);
  int start = __builtin_amdgcn_readfirstlane(rowptr[wid]);
  int end = __builtin_amdgcn_readfirstlane(rowptr[wid + 1]);
  float4 A0, A1, A2, A3;
  float2 X;
  int e_n, s_n;
  {
    int jc = min(start + half, end - 1);
    int e_c = eperm[jc], s_c = sperm[jc];
    const float4* p4 = (const float4*)((e_c < E)
                           ? edge_attr + (size_t)e_c * 16
                           : loop_attr + (size_t)(e_c - E) * 16);
    A0 = p4[0]; A1 = p4[1]; A2 = p4[2]; A3 = p4[3];
    X = *(const float2*)(xl + (size_t)s_c * 64 + ch);
    int j1 = min(start + 2 + half, end - 1);
    e_n = eperm[j1];
    s_n = sperm[j1];
  }
  float m = -1e30f, sden = 0.f, accx = 0.f, accy = 0.f;
  for (int j = start; j < end; j += 2) {
    int j2 = min(j + 4 + half, end - 1);
    int e2 = eperm[j2], s2 = sperm[j2];
    const float4* p4 = (const float4*)((e_n < E)
                           ? edge_attr + (size_t)e_n * 16
                           : loop_attr + (size_t)(e_n - E) * 16);
    float4 B0 = p4[0], B1 = p4[1], B2 = p4[2], B3 = p4[3];
    float2 Y = *(const float2*)(xl + (size_t)s_n * 64 + ch);
    float av[16] = {A0.x, A0.y, A0.z, A0.w, A1.x, A1.y, A1.z, A1.w,
                    A2.x, A2.y, A2.z, A2.w, A3.x, A3.y, A3.z, A3.w};
    float ex = 0.f, ey = 0.f;
#pragma unroll
    for (int k = 0; k < 16; k++) {
      ex = fmaf(av[k], we[k].x, ex);
      ey = fmaf(av[k], we[k].y, ey);
    }
    float mx = X.x + xr2.x + ex;
    float my = X.y + xr2.y + ey;
    mx = (mx >= 0.f) ? mx : 0.2f * mx;
    my = (my >= 0.f) ? my : 0.2f * my;
    float p = half_sum(fmaf(at2.x, mx, at2.y * my));
    bool dead = (j + half) >= end;  // odd-length tail in half 1
    p = dead ? -1e30f : p;
    float nm = fmaxf(m, p);
    float r = __expf(m - nm), ep = __expf(p - nm);
    ep = dead ? 0.f : ep;
    sden = fmaf(sden, r, ep);
    accx = fmaf(accx, r, ep * X.x);
    accy = fmaf(accy, r, ep * X.y);
    m = nm;
    A0 = B0; A1 = B1; A2 = B2; A3 = B3; X = Y;
    e_n = e2; s_n = s2;
  }
  // merge the two half-wave online-softmax states
  float mo = __shfl_xor(m, 32, 64);
  float so = __shfl_xor(sden, 32, 64);
  float aox = __shfl_xor(accx, 32, 64);
  float aoy = __shfl_xor(accy, 32, 64);
  float M = fmaxf(m, mo);
  float ra = __expf(m - M), rb = __expf(mo - M);
  float S = fmaf(sden, ra, so * rb);
  float AX = fmaf(accx, ra, aox * rb);
  float AY = fmaf(accy, ra, aoy * rb);
  float inv = 1.f / S;
  if (half == 0) {
    float2 b2 = *(const float2*)(bias + ch);
    *(float2*)(out + (size_t)wid * 64 + ch) =
        make_float2(fmaf(AX, inv, b2.x), fmaf(AY, inv, b2.y));
  }
}

// 4 edges per wave; 16 lanes x float4 per edge.
__global__ __launch_bounds__(256) void edge_mlp_kernel(
    const int* __restrict__ src, const int* __restrict__ dst,
    const float* __restrict__ aa, const float* __restrict__ bb,
    const float* __restrict__ Wm2, const float* __restrict__ bm2,
    float* __restrict__ out, int E) {
  int t = blockIdx.x * 256 + threadIdx.x;
  int eid = t >> 4;
  if (eid >= E) return;
  int g = threadIdx.x & 15;
  float4 w = ((const float4*)Wm2)[g];
  int s = src[eid], d = dst[eid];
  float4 za = ((const float4*)aa)[(size_t)s * 16 + g];
  float4 zb = ((const float4*)bb)[(size_t)d * 16 + g];
  float p = fmaxf(za.x + zb.x, 0.f) * w.x;
  p = fmaf(fmaxf(za.y + zb.y, 0.f), w.y, p);
  p = fmaf(fmaxf(za.z + zb.z, 0.f), w.z, p);
  p = fmaf(fmaxf(za.w + zb.w, 0.f), w.w, p);
#pragma unroll
  for (int o = 8; o > 0; o >>= 1) p += __shfl_xor(p, o, 64);
  if (g == 0) out[eid] = p + bm2[0];
}

extern "C" void kernel_launch(void* const* d_in, const int* in_sizes, int n_in,
                              void* d_out, int out_size, void* d_ws,
                              size_t ws_size, hipStream_t stream) {
  const float* x = (const float*)d_in[0];
  const int* ei = (const int*)d_in[1];
  const float* edge_attr = (const float*)d_in[2];
  const float* Wl1 = (const float*)d_in[3];
  const float* bl1 = (const float*)d_in[4];
  const float* Wr1 = (const float*)d_in[5];
  const float* br1 = (const float*)d_in[6];
  const float* We1 = (const float*)d_in[7];
  const float* att1 = (const float*)d_in[8];
  const float* b1 = (const float*)d_in[9];
  const float* Wl2 = (const float*)d_in[10];
  const float* bl2 = (const float*)d_in[11];
  const float* Wr2 = (const float*)d_in[12];
  const float* br2 = (const float*)d_in[13];
  const float* We2 = (const float*)d_in[14];
  const float* att2 = (const float*)d_in[15];
  const float* b2 = (const float*)d_in[16];
  const float* Wm1 = (const float*)d_in[17];
  const float* bm1 = (const float*)d_in[18];
  const float* Wm2 = (const float*)d_in[19];
  const float* bm2 = (const float*)d_in[20];

  const int Nn = in_sizes[0] / 128;  // 50000
  const int E = in_sizes[1] / 2;     // 800000
  const int Et = E + Nn;             // 850000
  const int* src = ei;
  const int* dst = ei + E;

  char* ws = (char*)d_ws;
  size_t off = 0;
  auto alloc = [&](size_t bytes) -> char* {
    char* p = ws + off;
    off += (bytes + 255) & ~(size_t)255;
    return p;
  };
  int* cnt = (int*)alloc((size_t)Nn * 4);
  float* loop_attr = (float*)alloc((size_t)Nn * 16 * 4);
  int* rowptr = (int*)alloc((size_t)(Nn + 1) * 4);
  int* cursor = (int*)alloc((size_t)Nn * 4);
  int* eperm = (int*)alloc((size_t)Et * 4);
  int* sperm = (int*)alloc((size_t)Et * 4);
  float* xl = (float*)alloc((size_t)Nn * 128 * 4);
  float* xr = (float*)alloc((size_t)Nn * 128 * 4);
  float* h1 = (float*)alloc((size_t)Nn * 128 * 4);
  float* h2 = (float*)alloc((size_t)Nn * 64 * 4);
  float* aa = xl;  // reuse after layer-2 node pass
  float* bb = xr;

  hipMemsetAsync(cnt, 0, (size_t)Nn * 4, stream);

  // --- graph preprocessing ---
  cnt_kernel<<<(E + 255) / 256, 256, 0, stream>>>(dst, cnt, E);
  scan_kernel<<<1, 1024, 0, stream>>>(cnt, rowptr, cursor, Nn);
  csr_build_kernel<<<(Et + 255) / 256, 256, 0, stream>>>(src, dst, cursor, eperm,
                                                         sperm, E, Et);
  loop_attr_kernel<<<(Nn + 3) / 4, 256, 0, stream>>>(rowptr, eperm, edge_attr,
                                                     loop_attr, Nn, E);

  // --- layer 1 (heads=2, hid=64) ---
  gemm_kernel<128, 128><<<(Nn + 63) / 64, 256, 0, stream>>>(x, Wl1, bl1, xl, Nn);
  gemm_kernel<128, 128><<<(Nn + 63) / 64, 256, 0, stream>>>(x, Wr1, br1, xr, Nn);
  node_fused2_kernel<1><<<(Nn + 3) / 4, 256, 0, stream>>>(
      rowptr, eperm, sperm, edge_attr, loop_attr, We1, att1, xl, xr, b1, h1, Nn, E);

  // --- layer 2 (heads=1, out=64) ---
  gemm_kernel<128, 64><<<(Nn + 63) / 64, 256, 0, stream>>>(h1, Wl2, bl2, xl, Nn);
  gemm_kernel<128, 64><<<(Nn + 63) / 64, 256, 0, stream>>>(h1, Wr2, br2, xr, Nn);
  node_fused1_kernel<<<(Nn + 3) / 4, 256, 0, stream>>>(
      rowptr, eperm, sperm, edge_attr, loop_attr, We2, att2, xl, xr, b2, h2, Nn, E);

  // --- edge MLP, folded: z = relu(h2[s]@Wm1_top + h2[d]@Wm1_bot + bm1) ---
  gemm_kernel<64, 64><<<(Nn + 63) / 64, 256, 0, stream>>>(h2, Wm1, nullptr, aa, Nn);
  gemm_kernel<64, 64><<<(Nn + 63) / 64, 256, 0, stream>>>(h2, Wm1 + 64 * 64, bm1,
                                                          bb, Nn);
  edge_mlp_kernel<<<(E * 16 + 255) / 256, 256, 0, stream>>>(src, dst, aa, bb,
                                                            Wm2, bm2,
                                                            (float*)d_out, E);
}

// Round 7
// 676.777 us; speedup vs baseline: 2.6880x; 1.1792x over previous
//
#include <hip/hip_runtime.h>
#include <cstdint>
#include <cstddef>

// ---------------------------------------------------------------------------
// GATv2 edge predictor, fp32 throughout.
//   preprocessing: cnt -> 3-kernel scan (blocksum/partials/write) -> csr (int2)
//   Self-loop handled ANALYTICALLY in the node pass: since mean(attr)@We =
//   mean(attr@We), accumulate per-edge eaW sums and process the self-loop last.
//   per GAT layer:
//     gemm2: xl = x@Wl+bl AND xr = x@Wr+br in one kernel (shared A tile)
//     node_fused{2,1}: one wave/node, ONLINE softmax, half-wave mapping,
//       We columns register-resident (launch_bounds(256,4) -> 128 VGPR cap),
//       2-deep pipeline, scalar (uniform) idx loads.
//   then: aa = h2@Wm1_top ; bb = h2@Wm1_bot+bm1 (edge MLP folded to nodes)
//   edge_mlp: 4 edges/wave, out[e] = relu(aa[s]+bb[d]).Wm2 + bm2
// ---------------------------------------------------------------------------

__device__ __forceinline__ float half_sum(float v) {
#pragma unroll
  for (int o = 1; o <= 16; o <<= 1) v += __shfl_xor(v, o, 64);
  return v;
}

__global__ __launch_bounds__(256) void cnt_kernel(const int* __restrict__ dst,
                                                  int* __restrict__ cnt, int E) {
  int e = blockIdx.x * 256 + threadIdx.x;
  if (e < E) atomicAdd(&cnt[dst[e]], 1);
}

// scan step 1: per-block sums of cnt
__global__ __launch_bounds__(256) void scan_blocksum_kernel(
    const int* __restrict__ cnt, int* __restrict__ partial, int Nn) {
  int i = blockIdx.x * 256 + threadIdx.x;
  int v = (i < Nn) ? cnt[i] : 0;
#pragma unroll
  for (int o = 32; o > 0; o >>= 1) v += __shfl_xor(v, o, 64);
  __shared__ int ws[4];
  if ((threadIdx.x & 63) == 0) ws[threadIdx.x >> 6] = v;
  __syncthreads();
  if (threadIdx.x == 0) partial[blockIdx.x] = ws[0] + ws[1] + ws[2] + ws[3];
}

// scan step 2: exclusive scan of block partials (single block; nb <= 256)
__global__ __launch_bounds__(256) void scan_partial_kernel(
    int* __restrict__ partial, int* __restrict__ rowptr, int nb, int Nn, int E) {
  __shared__ int buf[256];
  int t = threadIdx.x;
  int v = (t < nb) ? partial[t] : 0;
  buf[t] = v;
  __syncthreads();
  for (int o = 1; o < 256; o <<= 1) {
    int u = (t >= o) ? buf[t - o] : 0;
    __syncthreads();
    buf[t] += u;
    __syncthreads();
  }
  partial[t] = (t == 0) ? 0 : buf[t - 1];  // exclusive prefix
  if (t == 0) rowptr[Nn] = E;
}

// scan step 3: block-local exclusive scan + block offset -> rowptr & cursor
__global__ __launch_bounds__(256) void scan_write_kernel(
    const int* __restrict__ cnt, const int* __restrict__ partial,
    int* __restrict__ rowptr, int* __restrict__ cursor, int Nn) {
  __shared__ int buf[256];
  int i = blockIdx.x * 256 + threadIdx.x;
  int t = threadIdx.x;
  int v = (i < Nn) ? cnt[i] : 0;
  buf[t] = v;
  __syncthreads();
  for (int o = 1; o < 256; o <<= 1) {
    int u = (t >= o) ? buf[t - o] : 0;
    __syncthreads();
    buf[t] += u;
    __syncthreads();
  }
  if (i < Nn) {
    int r = partial[blockIdx.x] + buf[t] - v;
    rowptr[i] = r;
    cursor[i] = r;
  }
}

// CSR by dst over REAL edges only; packed (e, s) per slot.
__global__ __launch_bounds__(256) void csr_build_kernel(
    const int* __restrict__ src, const int* __restrict__ dst,
    int* __restrict__ cursor, int2* __restrict__ es, int E) {
  int e = blockIdx.x * 256 + threadIdx.x;
  if (e >= E) return;
  int s = src[e], d = dst[e];
  int pos = atomicAdd(&cursor[d], 1);
  es[pos] = make_int2(e, s);
}

// Dual GEMM: C1[M,NC] = A@W1 (+b1), C2[M,NC] = A@W2 (+b2); shared A tile.
template <int K, int NC>
__global__ __launch_bounds__(256, 4) void gemm2_kernel(
    const float* __restrict__ A, const float* __restrict__ W1,
    const float* __restrict__ b1, float* __restrict__ C1,
    const float* __restrict__ W2, const float* __restrict__ b2,
    float* __restrict__ C2, int M) {
  const int BM = 64;
  const int CQ = NC / 4;           // col quads per row
  const int RP = BM / (256 / CQ);  // rows per thread
  __shared__ float Alds[BM * K];
  int row0 = blockIdx.x * BM;
  for (int i = threadIdx.x; i < BM * K / 4; i += 256) {
    int r = i / (K / 4);
    float4 v = make_float4(0.f, 0.f, 0.f, 0.f);
    if (row0 + r < M) v = ((const float4*)A)[(size_t)(row0 + r) * (K / 4) + (i % (K / 4))];
    ((float4*)Alds)[i] = v;
  }
  __syncthreads();
  int cq = threadIdx.x % CQ;
  int rg = threadIdx.x / CQ;
  float4 acc1[RP], acc2[RP];
#pragma unroll
  for (int r = 0; r < RP; r++) {
    acc1[r] = make_float4(0.f, 0.f, 0.f, 0.f);
    acc2[r] = make_float4(0.f, 0.f, 0.f, 0.f);
  }
  const float4* W14 = (const float4*)W1;
  const float4* W24 = (const float4*)W2;
  for (int k = 0; k < K; k += 4) {
    float4 u0 = W14[(size_t)(k + 0) * CQ + cq];
    float4 u1 = W14[(size_t)(k + 1) * CQ + cq];
    float4 u2 = W14[(size_t)(k + 2) * CQ + cq];
    float4 u3 = W14[(size_t)(k + 3) * CQ + cq];
    float4 v0 = W24[(size_t)(k + 0) * CQ + cq];
    float4 v1 = W24[(size_t)(k + 1) * CQ + cq];
    float4 v2 = W24[(size_t)(k + 2) * CQ + cq];
    float4 v3 = W24[(size_t)(k + 3) * CQ + cq];
#pragma unroll
    for (int r = 0; r < RP; r++) {
      float4 a = ((const float4*)Alds)[(rg * RP + r) * (K / 4) + (k >> 2)];
      acc1[r].x = fmaf(a.x, u0.x, acc1[r].x);
      acc1[r].y = fmaf(a.x, u0.y, acc1[r].y);
      acc1[r].z = fmaf(a.x, u0.z, acc1[r].z);
      acc1[r].w = fmaf(a.x, u0.w, acc1[r].w);
      acc1[r].x = fmaf(a.y, u1.x, acc1[r].x);
      acc1[r].y = fmaf(a.y, u1.y, acc1[r].y);
      acc1[r].z = fmaf(a.y, u1.z, acc1[r].z);
      acc1[r].w = fmaf(a.y, u1.w, acc1[r].w);
      acc1[r].x = fmaf(a.z, u2.x, acc1[r].x);
      acc1[r].y = fmaf(a.z, u2.y, acc1[r].y);
      acc1[r].z = fmaf(a.z, u2.z, acc1[r].z);
      acc1[r].w = fmaf(a.z, u2.w, acc1[r].w);
      acc1[r].x = fmaf(a.w, u3.x, acc1[r].x);
      acc1[r].y = fmaf(a.w, u3.y, acc1[r].y);
      acc1[r].z = fmaf(a.w, u3.z, acc1[r].z);
      acc1[r].w = fmaf(a.w, u3.w, acc1[r].w);
      acc2[r].x = fmaf(a.x, v0.x, acc2[r].x);
      acc2[r].y = fmaf(a.x, v0.y, acc2[r].y);
      acc2[r].z = fmaf(a.x, v0.z, acc2[r].z);
      acc2[r].w = fmaf(a.x, v0.w, acc2[r].w);
      acc2[r].x = fmaf(a.y, v1.x, acc2[r].x);
      acc2[r].y = fmaf(a.y, v1.y, acc2[r].y);
      acc2[r].z = fmaf(a.y, v1.z, acc2[r].z);
      acc2[r].w = fmaf(a.y, v1.w, acc2[r].w);
      acc2[r].x = fmaf(a.z, v2.x, acc2[r].x);
      acc2[r].y = fmaf(a.z, v2.y, acc2[r].y);
      acc2[r].z = fmaf(a.z, v2.z, acc2[r].z);
      acc2[r].w = fmaf(a.z, v2.w, acc2[r].w);
      acc2[r].x = fmaf(a.w, v3.x, acc2[r].x);
      acc2[r].y = fmaf(a.w, v3.y, acc2[r].y);
      acc2[r].z = fmaf(a.w, v3.z, acc2[r].z);
      acc2[r].w = fmaf(a.w, v3.w, acc2[r].w);
    }
  }
  float4 bb1 = b1 ? ((const float4*)b1)[cq] : make_float4(0.f, 0.f, 0.f, 0.f);
  float4 bb2 = b2 ? ((const float4*)b2)[cq] : make_float4(0.f, 0.f, 0.f, 0.f);
#pragma unroll
  for (int r = 0; r < RP; r++) {
    int row = row0 + rg * RP + r;
    if (row < M) {
      ((float4*)C1)[(size_t)row * CQ + cq] =
          make_float4(acc1[r].x + bb1.x, acc1[r].y + bb1.y, acc1[r].z + bb1.z,
                      acc1[r].w + bb1.w);
      ((float4*)C2)[(size_t)row * CQ + cq] =
          make_float4(acc2[r].x + bb2.x, acc2[r].y + bb2.y, acc2[r].z + bb2.z,
                      acc2[r].w + bb2.w);
    }
  }
}

// H=2 fused node pass: lanes 0-31 = head0, lanes 32-63 = head1, float2 ch/lane.
// Self-loop processed last from accumulated eaW sums (linearity of mean@We).
template <int ELU>
__global__ __launch_bounds__(256, 4) void node_fused2_kernel(
    const int* __restrict__ rowptr, const int2* __restrict__ es,
    const float* __restrict__ edge_attr, const float* __restrict__ We,
    const float* __restrict__ att, const float* __restrict__ xl,
    const float* __restrict__ xr, const float* __restrict__ bias,
    float* __restrict__ out, int Nn) {
  int wid = blockIdx.x * 4 + (threadIdx.x >> 6);
  if (wid >= Nn) return;
  int l = threadIdx.x & 63;
  int ch = ((l >> 5) << 6) | ((l & 31) << 1);  // head*64 + 2*q
  float2 we[16];
#pragma unroll
  for (int k = 0; k < 16; k++) we[k] = *(const float2*)(We + k * 128 + ch);
  float2 xr2 = *(const float2*)(xr + (size_t)wid * 128 + ch);
  float2 at2 = *(const float2*)(att + ch);
  int start = __builtin_amdgcn_readfirstlane(rowptr[wid]);
  int end = __builtin_amdgcn_readfirstlane(rowptr[wid + 1]);
  float m = -1e30f, sden = 0.f, accx = 0.f, accy = 0.f;
  float sax = 0.f, say = 0.f;  // sum of eaW over real edges (for self-loop)
  if (end > start) {
    float4 A0, A1, A2, A3;
    float2 X;
    int2 en;
    {
      int2 ec = es[start];
      const float4* p4 = (const float4*)(edge_attr + (size_t)ec.x * 16);
      A0 = p4[0]; A1 = p4[1]; A2 = p4[2]; A3 = p4[3];
      X = *(const float2*)(xl + (size_t)ec.y * 128 + ch);
      en = es[min(start + 1, end - 1)];
    }
    for (int j = start; j < end; ++j) {
      int2 e2 = es[min(j + 2, end - 1)];
      const float4* p4 = (const float4*)(edge_attr + (size_t)en.x * 16);
      float4 B0 = p4[0], B1 = p4[1], B2 = p4[2], B3 = p4[3];
      float2 Y = *(const float2*)(xl + (size_t)en.y * 128 + ch);
      float av[16] = {A0.x, A0.y, A0.z, A0.w, A1.x, A1.y, A1.z, A1.w,
                      A2.x, A2.y, A2.z, A2.w, A3.x, A3.y, A3.z, A3.w};
      float ex = 0.f, ey = 0.f;
#pragma unroll
      for (int k = 0; k < 16; k++) {
        ex = fmaf(av[k], we[k].x, ex);
        ey = fmaf(av[k], we[k].y, ey);
      }
      sax += ex;
      say += ey;
      float mx = X.x + xr2.x + ex;
      float my = X.y + xr2.y + ey;
      mx = (mx >= 0.f) ? mx : 0.2f * mx;  // LeakyReLU(0.2)
      my = (my >= 0.f) ? my : 0.2f * my;
      float p = half_sum(fmaf(at2.x, mx, at2.y * my));
      float nm = fmaxf(m, p);
      float r = __expf(m - nm), ep = __expf(p - nm);
      sden = fmaf(sden, r, ep);
      accx = fmaf(accx, r, ep * X.x);
      accy = fmaf(accy, r, ep * X.y);
      m = nm;
      A0 = B0; A1 = B1; A2 = B2; A3 = B3; X = Y;
      en = e2;
    }
  }
  // self loop: eaW = mean over incident edges (0 if none)
  {
    float denom = 1.f / fmaxf((float)(end - start), 1.f);
    float2 Xs = *(const float2*)(xl + (size_t)wid * 128 + ch);
    float mx = Xs.x + xr2.x + sax * denom;
    float my = Xs.y + xr2.y + say * denom;
    mx = (mx >= 0.f) ? mx : 0.2f * mx;
    my = (my >= 0.f) ? my : 0.2f * my;
    float p = half_sum(fmaf(at2.x, mx, at2.y * my));
    float nm = fmaxf(m, p);
    float r = __expf(m - nm), ep = __expf(p - nm);
    sden = fmaf(sden, r, ep);
    accx = fmaf(accx, r, ep * Xs.x);
    accy = fmaf(accy, r, ep * Xs.y);
  }
  float inv = 1.f / sden;
  float2 b2 = *(const float2*)(bias + ch);
  float vx = fmaf(accx, inv, b2.x);
  float vy = fmaf(accy, inv, b2.y);
  if (ELU) {
    vx = (vx > 0.f) ? vx : expm1f(vx);
    vy = (vy > 0.f) ? vy : expm1f(vy);
  }
  *(float2*)(out + (size_t)wid * 128 + ch) = make_float2(vx, vy);
}

// H=1 fused node pass: half-wave per edge (2 edges/iteration), float2 ch/lane,
// state merge across halves, then analytic self-loop.
__global__ __launch_bounds__(256, 4) void node_fused1_kernel(
    const int* __restrict__ rowptr, const int2* __restrict__ es,
    const float* __restrict__ edge_attr, const float* __restrict__ We,
    const float* __restrict__ att, const float* __restrict__ xl,
    const float* __restrict__ xr, const float* __restrict__ bias,
    float* __restrict__ out, int Nn) {
  int wid = blockIdx.x * 4 + (threadIdx.x >> 6);
  if (wid >= Nn) return;
  int l = threadIdx.x & 63;
  int half = l >> 5;
  int ch = (l & 31) << 1;
  float2 we[16];
#pragma unroll
  for (int k = 0; k < 16; k++) we[k] = *(const float2*)(We + k * 64 + ch);
  float2 xr2 = *(const float2*)(xr + (size_t)wid * 64 + ch);
  float2 at2 = *(const float2*)(att + ch);
  int start = __builtin_amdgcn_readfirstlane(rowptr[wid]);
  int end = __builtin_amdgcn_readfirstlane(rowptr[wid + 1]);
  float m = -1e30f, sden = 0.f, accx = 0.f, accy = 0.f;
  float sax = 0.f, say = 0.f;
  if (end > start) {
    float4 A0, A1, A2, A3;
    float2 X;
    int2 en;
    {
      int jc = min(start + half, end - 1);
      int2 ec = es[jc];
      const float4* p4 = (const float4*)(edge_attr + (size_t)ec.x * 16);
      A0 = p4[0]; A1 = p4[1]; A2 = p4[2]; A3 = p4[3];
      X = *(const float2*)(xl + (size_t)ec.y * 64 + ch);
      en = es[min(start + 2 + half, end - 1)];
    }
    for (int j = start; j < end; j += 2) {
      int2 e2 = es[min(j + 4 + half, end - 1)];
      const float4* p4 = (const float4*)(edge_attr + (size_t)en.x * 16);
      float4 B0 = p4[0], B1 = p4[1], B2 = p4[2], B3 = p4[3];
      float2 Y = *(const float2*)(xl + (size_t)en.y * 64 + ch);
      float av[16] = {A0.x, A0.y, A0.z, A0.w, A1.x, A1.y, A1.z, A1.w,
                      A2.x, A2.y, A2.z, A2.w, A3.x, A3.y, A3.z, A3.w};
      float ex = 0.f, ey = 0.f;
#pragma unroll
      for (int k = 0; k < 16; k++) {
        ex = fmaf(av[k], we[k].x, ex);
        ey = fmaf(av[k], we[k].y, ey);
      }
      bool dead = (j + half) >= end;  // odd-length tail in half 1
      sax += dead ? 0.f : ex;
      say += dead ? 0.f : ey;
      float mx = X.x + xr2.x + ex;
      float my = X.y + xr2.y + ey;
      mx = (mx >= 0.f) ? mx : 0.2f * mx;
      my = (my >= 0.f) ? my : 0.2f * my;
      float p = half_sum(fmaf(at2.x, mx, at2.y * my));
      p = dead ? -1e30f : p;
      float nm = fmaxf(m, p);
      float r = __expf(m - nm), ep = __expf(p - nm);
      ep = dead ? 0.f : ep;
      sden = fmaf(sden, r, ep);
      accx = fmaf(accx, r, ep * X.x);
      accy = fmaf(accy, r, ep * X.y);
      m = nm;
      A0 = B0; A1 = B1; A2 = B2; A3 = B3; X = Y;
      en = e2;
    }
  }
  // merge the two half-wave states
  float mo = __shfl_xor(m, 32, 64);
  float so = __shfl_xor(sden, 32, 64);
  float aox = __shfl_xor(accx, 32, 64);
  float aoy = __shfl_xor(accy, 32, 64);
  float M = fmaxf(m, mo);
  float ra = __expf(m - M), rb = __expf(mo - M);
  float S = fmaf(sden, ra, so * rb);
  float AX = fmaf(accx, ra, aox * rb);
  float AY = fmaf(accy, ra, aoy * rb);
  float saxt = sax + __shfl_xor(sax, 32, 64);
  float sayt = say + __shfl_xor(say, 32, 64);
  // self loop (identical in both halves after merge)
  {
    float denom = 1.f / fmaxf((float)(end - start), 1.f);
    float2 Xs = *(const float2*)(xl + (size_t)wid * 64 + ch);
    float mx = Xs.x + xr2.x + saxt * denom;
    float my = Xs.y + xr2.y + sayt * denom;
    mx = (mx >= 0.f) ? mx : 0.2f * mx;
    my = (my >= 0.f) ? my : 0.2f * my;
    float p = half_sum(fmaf(at2.x, mx, at2.y * my));
    float nm = fmaxf(M, p);
    float r = __expf(M - nm), ep = __expf(p - nm);
    S = fmaf(S, r, ep);
    AX = fmaf(AX, r, ep * Xs.x);
    AY = fmaf(AY, r, ep * Xs.y);
  }
  if (half == 0) {
    float inv = 1.f / S;
    float2 b2 = *(const float2*)(bias + ch);
    *(float2*)(out + (size_t)wid * 64 + ch) =
        make_float2(fmaf(AX, inv, b2.x), fmaf(AY, inv, b2.y));
  }
}

// 4 edges per wave; 16 lanes x float4 per edge.
__global__ __launch_bounds__(256) void edge_mlp_kernel(
    const int* __restrict__ src, const int* __restrict__ dst,
    const float* __restrict__ aa, const float* __restrict__ bb,
    const float* __restrict__ Wm2, const float* __restrict__ bm2,
    float* __restrict__ out, int E) {
  int t = blockIdx.x * 256 + threadIdx.x;
  int eid = t >> 4;
  if (eid >= E) return;
  int g = threadIdx.x & 15;
  float4 w = ((const float4*)Wm2)[g];
  int s = src[eid], d = dst[eid];
  float4 za = ((const float4*)aa)[(size_t)s * 16 + g];
  float4 zb = ((const float4*)bb)[(size_t)d * 16 + g];
  float p = fmaxf(za.x + zb.x, 0.f) * w.x;
  p = fmaf(fmaxf(za.y + zb.y, 0.f), w.y, p);
  p = fmaf(fmaxf(za.z + zb.z, 0.f), w.z, p);
  p = fmaf(fmaxf(za.w + zb.w, 0.f), w.w, p);
#pragma unroll
  for (int o = 8; o > 0; o >>= 1) p += __shfl_xor(p, o, 64);
  if (g == 0) out[eid] = p + bm2[0];
}

extern "C" void kernel_launch(void* const* d_in, const int* in_sizes, int n_in,
                              void* d_out, int out_size, void* d_ws,
                              size_t ws_size, hipStream_t stream) {
  const float* x = (const float*)d_in[0];
  const int* ei = (const int*)d_in[1];
  const float* edge_attr = (const float*)d_in[2];
  const float* Wl1 = (const float*)d_in[3];
  const float* bl1 = (const float*)d_in[4];
  const float* Wr1 = (const float*)d_in[5];
  const float* br1 = (const float*)d_in[6];
  const float* We1 = (const float*)d_in[7];
  const float* att1 = (const float*)d_in[8];
  const float* b1 = (const float*)d_in[9];
  const float* Wl2 = (const float*)d_in[10];
  const float* bl2 = (const float*)d_in[11];
  const float* Wr2 = (const float*)d_in[12];
  const float* br2 = (const float*)d_in[13];
  const float* We2 = (const float*)d_in[14];
  const float* att2 = (const float*)d_in[15];
  const float* b2 = (const float*)d_in[16];
  const float* Wm1 = (const float*)d_in[17];
  const float* bm1 = (const float*)d_in[18];
  const float* Wm2 = (const float*)d_in[19];
  const float* bm2 = (const float*)d_in[20];

  const int Nn = in_sizes[0] / 128;  // 50000
  const int E = in_sizes[1] / 2;     // 800000
  const int* src = ei;
  const int* dst = ei + E;
  const int nb = (Nn + 255) / 256;   // scan blocks (196 <= 256)

  char* ws = (char*)d_ws;
  size_t off = 0;
  auto alloc = [&](size_t bytes) -> char* {
    char* p = ws + off;
    off += (bytes + 255) & ~(size_t)255;
    return p;
  };
  int* cnt = (int*)alloc((size_t)Nn * 4);
  int* rowptr = (int*)alloc((size_t)(Nn + 1) * 4);
  int* cursor = (int*)alloc((size_t)Nn * 4);
  int* partial = (int*)alloc(256 * 4);
  int2* es = (int2*)alloc((size_t)E * 8);
  float* xl = (float*)alloc((size_t)Nn * 128 * 4);
  float* xr = (float*)alloc((size_t)Nn * 128 * 4);
  float* h1 = (float*)alloc((size_t)Nn * 128 * 4);
  float* h2 = (float*)alloc((size_t)Nn * 64 * 4);
  float* aa = xl;  // reuse after layer-2 node pass
  float* bb = xr;

  hipMemsetAsync(cnt, 0, (size_t)Nn * 4, stream);

  // --- graph preprocessing ---
  cnt_kernel<<<(E + 255) / 256, 256, 0, stream>>>(dst, cnt, E);
  scan_blocksum_kernel<<<nb, 256, 0, stream>>>(cnt, partial, Nn);
  scan_partial_kernel<<<1, 256, 0, stream>>>(partial, rowptr, nb, Nn, E);
  scan_write_kernel<<<nb, 256, 0, stream>>>(cnt, partial, rowptr, cursor, Nn);
  csr_build_kernel<<<(E + 255) / 256, 256, 0, stream>>>(src, dst, cursor, es, E);

  // --- layer 1 (heads=2, hid=64) ---
  gemm2_kernel<128, 128><<<(Nn + 63) / 64, 256, 0, stream>>>(
      x, Wl1, bl1, xl, Wr1, br1, xr, Nn);
  node_fused2_kernel<1><<<(Nn + 3) / 4, 256, 0, stream>>>(
      rowptr, es, edge_attr, We1, att1, xl, xr, b1, h1, Nn);

  // --- layer 2 (heads=1, out=64) ---
  gemm2_kernel<128, 64><<<(Nn + 63) / 64, 256, 0, stream>>>(
      h1, Wl2, bl2, xl, Wr2, br2, xr, Nn);
  node_fused1_kernel<<<(Nn + 3) / 4, 256, 0, stream>>>(
      rowptr, es, edge_attr, We2, att2, xl, xr, b2, h2, Nn);

  // --- edge MLP, folded: z = relu(h2[s]@Wm1_top + h2[d]@Wm1_bot + bm1) ---
  gemm2_kernel<64, 64><<<(Nn + 63) / 64, 256, 0, stream>>>(
      h2, Wm1, nullptr, aa, Wm1 + 64 * 64, bm1, bb, Nn);
  edge_mlp_kernel<<<(E * 16 + 255) / 256, 256, 0, stream>>>(src, dst, aa, bb,
                                                            Wm2, bm2,
                                                            (float*)d_out, E);
}